// Round 6
// baseline (429.132 us; speedup 1.0000x reference)
//
#include <hip/hip_runtime.h>

// GAT layer: N=8192, IN_DIM=128, OUT_DIM=64, alpha=0.2
// out = elu( softmax_row( mask(lrelu(s1_i + s2_j), adj) ) @ Wh )
//
// R6: defeat the vmcnt in-order prefetch kill.
//  Key identity: exp2(lrelu(e)) = max(exp2(e), exp2(0.2e)), separable:
//    p_ij = max(F1_i*T1_j, F2_i*T2_j) * adj_ij   (all factors <= 1, fp16)
//  -> hot loop is pure packed-fp16 pk_mul/pk_max (no exp2), tables L2-hot.
//  Per-tile issue order: [cur B (L2)] -> [next adj+TT prefetch] -> P build
//  -> MFMA. MFMA's B-wait is vmcnt(5): the adj prefetch stays in flight
//  across the whole tile (in-order vmcnt no longer drains it).

#define N 8192
#define IN_DIM 128
#define OUT_DIM 64
#define ALPHA 0.2f
#define LOG2E 1.44269504088896f
#define JC 16            // j-chunks
#define CW (N / JC)      // 512 cols per chunk
#define TW 64            // cols per tile
#define NT (CW / TW)     // 8 tiles
#define LDP 72           // LDS row stride (halfs)

typedef _Float16 half8 __attribute__((ext_vector_type(8)));
typedef _Float16 h2 __attribute__((ext_vector_type(2)));
typedef float f32x4 __attribute__((ext_vector_type(4)));

// ---------------------------------------------------------------------------
// Kernel 1: Wh = x@W (fp16, transposed [f][i]); s1L/s2L = log2e * scores
// ---------------------------------------------------------------------------
__global__ __launch_bounds__(64) void wh_kernel(
    const float* __restrict__ x, const float* __restrict__ W,
    const float* __restrict__ a, _Float16* __restrict__ Wh_t,
    float* __restrict__ s1L, float* __restrict__ s2L) {
  __shared__ float xs[IN_DIM];
  const int i = blockIdx.x;
  const int t = threadIdx.x;

  xs[t]      = x[(size_t)i * IN_DIM + t];
  xs[t + 64] = x[(size_t)i * IN_DIM + 64 + t];
  __syncthreads();

  float wh = 0.f;
#pragma unroll
  for (int d = 0; d < IN_DIM; ++d) wh = fmaf(xs[d], W[d * OUT_DIM + t], wh);

  Wh_t[(size_t)t * N + i] = (_Float16)wh;

  float p1 = wh * a[t];
  float p2 = wh * a[64 + t];
#pragma unroll
  for (int off = 32; off; off >>= 1) {
    p1 += __shfl_down(p1, off);
    p2 += __shfl_down(p2, off);
  }
  if (t == 0) {
    s1L[i] = p1 * LOG2E;
    s2L[i] = p2 * LOG2E;
  }
}

// ---------------------------------------------------------------------------
// Kernel 2: mm = {m1, ML}: m1 = max(s1L), ML = lrelu(m1 + max(s2L)).
// ---------------------------------------------------------------------------
__global__ __launch_bounds__(256) void max_kernel(
    const float* __restrict__ s1L, const float* __restrict__ s2L,
    float* __restrict__ mm) {
  __shared__ float red[8];
  const int t = threadIdx.x;
  float m1 = -1e30f, m2 = -1e30f;
  for (int idx = t; idx < N; idx += 256) {
    m1 = fmaxf(m1, s1L[idx]);
    m2 = fmaxf(m2, s2L[idx]);
  }
#pragma unroll
  for (int off = 32; off; off >>= 1) {
    m1 = fmaxf(m1, __shfl_down(m1, off));
    m2 = fmaxf(m2, __shfl_down(m2, off));
  }
  if ((t & 63) == 0) {
    red[t >> 6] = m1;
    red[4 + (t >> 6)] = m2;
  }
  __syncthreads();
  if (t == 0) {
    m1 = fmaxf(fmaxf(red[0], red[1]), fmaxf(red[2], red[3]));
    m2 = fmaxf(fmaxf(red[4], red[5]), fmaxf(red[6], red[7]));
    float e = m1 + m2;
    mm[0] = m1;
    mm[1] = fmaxf(e, ALPHA * e);
  }
}

// ---------------------------------------------------------------------------
// Kernel 3: factor tables. F1i*T1j = 2^(s1L+s2L-ML); F2i*T2j = 2^(.2(s1L+s2L)-ML)
// Split-shift keeps every factor <= 1 (no fp16 overflow):
//   Fi[i] = half2{ 2^(s1L-m1), 2^(.2(s1L-m1)) }
//   TT[j/4] = 16B { T1[j..j+3], T2[j..j+3] },  T1 = 2^(s2L-(ML-m1)),
//   T2 = 2^(.2*s2L-(ML-.2*m1))
// ---------------------------------------------------------------------------
__global__ __launch_bounds__(256) void ftab_kernel(
    const float* __restrict__ s1L, const float* __restrict__ s2L,
    const float* __restrict__ mm, unsigned int* __restrict__ Fi,
    _Float16* __restrict__ TTh) {
  const int j = blockIdx.x * 256 + threadIdx.x;
  const float m1 = mm[0], ML = mm[1];

  const _Float16 f1 = (_Float16)exp2f(s1L[j] - m1);
  const _Float16 f2 = (_Float16)exp2f(0.2f * (s1L[j] - m1));
  h2 f;
  f[0] = f1;
  f[1] = f2;
  Fi[j] = __builtin_bit_cast(unsigned int, f);

  TTh[(j >> 2) * 8 + (j & 3)]     = (_Float16)exp2f(s2L[j] - (ML - m1));
  TTh[(j >> 2) * 8 + 4 + (j & 3)] = (_Float16)exp2f(0.2f * s2L[j] - (ML - 0.2f * m1));
}

// ---------------------------------------------------------------------------
// Kernel 4: pack B-fragments (unchanged from R5): contiguous per (kt,fg,lane).
// ---------------------------------------------------------------------------
__global__ __launch_bounds__(256) void bpack_kernel(
    const _Float16* __restrict__ Wh_t, _Float16* __restrict__ Bpack) {
  const int kt = blockIdx.x;
  const int t = threadIdx.x;
  const int fg = t >> 6;
  const int lane = t & 63;
  const int q = (t >> 4) & 3;
  const int r16 = t & 15;
  const half8 v =
      *(const half8*)(Wh_t + (size_t)(fg * 16 + r16) * N + kt * 32 + q * 8);
  *(half8*)(Bpack + ((size_t)(kt * 4 + fg) * 64 + lane) * 8) = v;
}

// ---------------------------------------------------------------------------
// Kernel 5: adj streamer. grid (N/64, JC); wave w: rows i0..i0+15,
// chunk cols [c*512,+512) in 8 tiles of 64. Per-wave LDS, no barriers.
// Load map: av[it] = int4 at row i0+4it+(lane>>4), cols (lane&15)*4
//   (4x256B segments per instr, 16 sequential row-streams per wave).
// ---------------------------------------------------------------------------
__global__ __launch_bounds__(256, 4) void attn_kernel(
    const int* __restrict__ adj, const _Float16* __restrict__ Bpack,
    const unsigned int* __restrict__ Fi, const uint4* __restrict__ TT,
    float* __restrict__ accp, float* __restrict__ lp) {
  __shared__ __align__(16) _Float16 Ps[4 * 16 * LDP];

  const int t = threadIdx.x;
  const int w = t >> 6;
  const int lane = t & 63;
  const int q = lane >> 4;
  const int r16 = lane & 15;
  const int r4 = lane >> 4;   // load-phase row within quad-group
  const int l16 = lane & 15;  // load-phase col group
  const int rb = (int)(gridDim.x - 1 - blockIdx.x);  // reverse: tail rows hot
  const int i0 = rb * 64 + w * 16;
  const int c = blockIdx.y;
  const int jb = c * CW;

  // per-row factor broadcasts: f1b/f2b[it] = {F,F} for row 4it+r4
  h2 f1b[4], f2b[4];
#pragma unroll
  for (int it = 0; it < 4; ++it) {
    const unsigned int u = Fi[i0 + 4 * it + r4];
    f1b[it] = __builtin_bit_cast(h2, (u & 0xFFFFu) * 0x00010001u);
    f2b[it] = __builtin_bit_cast(h2, (u >> 16) * 0x00010001u);
  }

  half8 bones;
#pragma unroll
  for (int e = 0; e < 8; ++e)
    bones[e] = (r16 == 0) ? (_Float16)1.0f : (_Float16)0.0f;

  f32x4 acc[5] = {{0.f, 0.f, 0.f, 0.f}, {0.f, 0.f, 0.f, 0.f},
                  {0.f, 0.f, 0.f, 0.f}, {0.f, 0.f, 0.f, 0.f},
                  {0.f, 0.f, 0.f, 0.f}};

  const int* ap = adj + (size_t)(i0 + r4) * N + jb + l16 * 4;
  _Float16* Pw = Ps + w * 16 * LDP;
  const _Float16* ldA = Pw + r16 * LDP + q * 8;
  _Float16* stP = Pw + r4 * LDP + l16 * 4;

  // prefetch tile 0 (adj + col table)
  int4 av[4];
#pragma unroll
  for (int it = 0; it < 4; ++it) av[it] = *(const int4*)(ap + it * 4 * N);
  uint4 tt = TT[(jb >> 2) + l16];

  for (int jt = 0; jt < NT; ++jt) {
    const int ktb = c * 16 + jt * 2;

    // (1) B loads for the CURRENT tile (L2-resident; issued FIRST so the
    //     MFMA's vmcnt wait leaves the adj prefetch below in flight)
    half8 bf[2][4];
#pragma unroll
    for (int ks = 0; ks < 2; ++ks)
#pragma unroll
      for (int fg = 0; fg < 4; ++fg)
        bf[ks][fg] = *(const half8*)(Bpack +
                                     ((size_t)((ktb + ks) * 4 + fg) * 64 + lane) * 8);

    // (2) prefetch NEXT tile adj + table
    const int jnoff = ((jt + 1) & (NT - 1)) * TW;  // wrap: harmless reload
    int4 nav[4];
#pragma unroll
    for (int it = 0; it < 4; ++it)
      nav[it] = *(const int4*)(ap + jnoff + it * 4 * N);
    const uint4 ntt = TT[((jb + jnoff) >> 2) + l16];

    // (3) P build (packed fp16, no transcendentals): 4 cols x 4 rows/lane
#pragma unroll
    for (int it = 0; it < 4; ++it) {
      const unsigned int mlo =
          (unsigned int)(av[it].x | (av[it].y << 16)) * 0x3C00u;
      const unsigned int mhi =
          (unsigned int)(av[it].z | (av[it].w << 16)) * 0x3C00u;
      const h2 t1lo = __builtin_bit_cast(h2, tt.x);
      const h2 t1hi = __builtin_bit_cast(h2, tt.y);
      const h2 t2lo = __builtin_bit_cast(h2, tt.z);
      const h2 t2hi = __builtin_bit_cast(h2, tt.w);
      h2 plo = __builtin_elementwise_max(f1b[it] * t1lo, f2b[it] * t2lo) *
               __builtin_bit_cast(h2, mlo);
      h2 phi = __builtin_elementwise_max(f1b[it] * t1hi, f2b[it] * t2hi) *
               __builtin_bit_cast(h2, mhi);
      uint2 pw;
      pw.x = __builtin_bit_cast(unsigned int, plo);
      pw.y = __builtin_bit_cast(unsigned int, phi);
      *(uint2*)(stP + it * 4 * LDP) = pw;
    }

    // (4) MFMA: A from per-wave LDS, B from regs (+ ones column -> row sums)
#pragma unroll
    for (int ks = 0; ks < 2; ++ks) {
      const half8 aF = *(const half8*)(ldA + ks * 32);
#pragma unroll
      for (int fg = 0; fg < 4; ++fg)
        acc[fg] =
            __builtin_amdgcn_mfma_f32_16x16x32_f16(aF, bf[ks][fg], acc[fg],
                                                   0, 0, 0);
      acc[4] =
          __builtin_amdgcn_mfma_f32_16x16x32_f16(aF, bones, acc[4], 0, 0, 0);
    }

#pragma unroll
    for (int it = 0; it < 4; ++it) av[it] = nav[it];
    tt = ntt;
  }

  // epilogue: C/D row = q*4+r, col = r16 (per fg block)
#pragma unroll
  for (int fg = 0; fg < 4; ++fg) {
#pragma unroll
    for (int r = 0; r < 4; ++r) {
      accp[((size_t)c * N + i0 + q * 4 + r) * OUT_DIM + fg * 16 + r16] =
          acc[fg][r];
    }
  }
  if (r16 == 0) {
#pragma unroll
    for (int r = 0; r < 4; ++r) lp[(size_t)c * N + i0 + q * 4 + r] = acc[4][r];
  }
}

// ---------------------------------------------------------------------------
// Kernel 6: combine JC partials, normalize, ELU.
// ---------------------------------------------------------------------------
__global__ __launch_bounds__(256) void reduce_kernel(
    const float* __restrict__ accp, const float* __restrict__ lp,
    float* __restrict__ out) {
  const int tid = blockIdx.x * 256 + threadIdx.x;
  const int i = tid >> 6;
  float s = 0.f, l = 0.f;
#pragma unroll
  for (int c = 0; c < JC; ++c) s += accp[(size_t)c * N * OUT_DIM + tid];
#pragma unroll
  for (int c = 0; c < JC; ++c) l += lp[(size_t)c * N + i];
  float v = s / l;
  out[tid] = v > 0.f ? v : expm1f(v);
}

// ---------------------------------------------------------------------------
extern "C" void kernel_launch(void* const* d_in, const int* in_sizes, int n_in,
                              void* d_out, int out_size, void* d_ws,
                              size_t ws_size, hipStream_t stream) {
  const float* x = (const float*)d_in[0];
  const int* adj = (const int*)d_in[1];
  const float* W = (const float*)d_in[2];
  const float* a = (const float*)d_in[3];
  float* out = (float*)d_out;

  char* ws = (char*)d_ws;
  _Float16* Wh_t = (_Float16*)ws;                   // 1 MiB
  float* s1L = (float*)(ws + (1u << 20));           // 32 KiB
  float* s2L = s1L + N;                             // 32 KiB
  float* mm = s2L + N;                              // 8 B
  _Float16* Bpack = (_Float16*)(ws + (2u << 20));   // 1 MiB
  unsigned int* Fi = (unsigned int*)(ws + (3u << 20));       // 32 KiB
  _Float16* TTh = (_Float16*)(ws + (3u << 20) + (512u << 10));  // 32 KiB
  float* accp = (float*)(ws + (4u << 20));          // JC*N*64*4 = 32 MiB
  float* lp = accp + (size_t)JC * N * OUT_DIM;      // 512 KiB

  wh_kernel<<<N, 64, 0, stream>>>(x, W, a, Wh_t, s1L, s2L);
  max_kernel<<<1, 256, 0, stream>>>(s1L, s2L, mm);
  ftab_kernel<<<N / 256, 256, 0, stream>>>(s1L, s2L, mm, Fi, TTh);
  bpack_kernel<<<N / 32, 256, 0, stream>>>(Wh_t, Bpack);
  attn_kernel<<<dim3(N / 64, JC), 256, 0, stream>>>(
      adj, Bpack, Fi, (const uint4*)TTh, accp, lp);
  reduce_kernel<<<N * OUT_DIM / 256, 256, 0, stream>>>(accp, lp, out);
}

// Round 8
// 426.543 us; speedup vs baseline: 1.0061x; 1.0061x over previous
//
#include <hip/hip_runtime.h>

// GAT layer: N=8192, IN_DIM=128, OUT_DIM=64, alpha=0.2
// out = elu( softmax_row( mask(lrelu(s1_i + s2_j), adj) ) @ Wh )
//
// R8: R5/R6 multi-kernel mechanics (known-good; R7's cooperative launch
// silently failed) + maximal-contiguity adj streaming:
//   every adj load = ONE row x 1 KB, all 64 lanes contiguous (the fill-kernel
//   shape that measures 6.7 TB/s). Wave sweeps its 16 rows one-load-per-row,
//   k-tile = 256 cols, P via per-wave LDS (no barriers), MFMA 8 k-steps from
//   LDS A-frags + L2-hot Bpack B-frags + ones-column row sums.
// P math: separable no-transcendental tables (R6-verified):
//   p_ij = max(F1_i*T1_j, F2_i*T2_j) * adj_ij, all factors <= 1 in fp16.

#define N 8192
#define IN_DIM 128
#define OUT_DIM 64
#define ALPHA 0.2f
#define LOG2E 1.44269504088896f
#define JC 8        // j-chunks -> grid (128, 8) = 1024 blocks = 4/CU
#define LDP 264     // LDS row stride in halfs (256 cols + 8 pad; 16B-aligned)

typedef _Float16 half8 __attribute__((ext_vector_type(8)));
typedef _Float16 h2 __attribute__((ext_vector_type(2)));
typedef float f32x4 __attribute__((ext_vector_type(4)));

static __device__ __forceinline__ h2 bc_h2(unsigned u) {
  return __builtin_bit_cast(h2, u);
}

// ---------------------------------------------------------------------------
// Kernel 1: Wh = x@W (fp16, transposed [f][i]); s1L/s2L = log2e * scores
// ---------------------------------------------------------------------------
__global__ __launch_bounds__(64) void wh_kernel(
    const float* __restrict__ x, const float* __restrict__ W,
    const float* __restrict__ a, _Float16* __restrict__ Wh_t,
    float* __restrict__ s1L, float* __restrict__ s2L) {
  __shared__ float xs[IN_DIM];
  const int i = blockIdx.x;
  const int t = threadIdx.x;

  xs[t]      = x[(size_t)i * IN_DIM + t];
  xs[t + 64] = x[(size_t)i * IN_DIM + 64 + t];
  __syncthreads();

  float wh = 0.f;
#pragma unroll
  for (int d = 0; d < IN_DIM; ++d) wh = fmaf(xs[d], W[d * OUT_DIM + t], wh);

  Wh_t[(size_t)t * N + i] = (_Float16)wh;

  float p1 = wh * a[t];
  float p2 = wh * a[64 + t];
#pragma unroll
  for (int off = 32; off; off >>= 1) {
    p1 += __shfl_down(p1, off);
    p2 += __shfl_down(p2, off);
  }
  if (t == 0) {
    s1L[i] = p1 * LOG2E;
    s2L[i] = p2 * LOG2E;
  }
}

// ---------------------------------------------------------------------------
// Kernel 2: mm = {m1, ML}: m1 = max(s1L), ML = lrelu(m1 + max(s2L)).
// ---------------------------------------------------------------------------
__global__ __launch_bounds__(256) void max_kernel(
    const float* __restrict__ s1L, const float* __restrict__ s2L,
    float* __restrict__ mm) {
  __shared__ float red[8];
  const int t = threadIdx.x;
  float m1 = -1e30f, m2 = -1e30f;
  for (int idx = t; idx < N; idx += 256) {
    m1 = fmaxf(m1, s1L[idx]);
    m2 = fmaxf(m2, s2L[idx]);
  }
#pragma unroll
  for (int off = 32; off; off >>= 1) {
    m1 = fmaxf(m1, __shfl_down(m1, off));
    m2 = fmaxf(m2, __shfl_down(m2, off));
  }
  if ((t & 63) == 0) {
    red[t >> 6] = m1;
    red[4 + (t >> 6)] = m2;
  }
  __syncthreads();
  if (t == 0) {
    m1 = fmaxf(fmaxf(red[0], red[1]), fmaxf(red[2], red[3]));
    m2 = fmaxf(fmaxf(red[4], red[5]), fmaxf(red[6], red[7]));
    float e = m1 + m2;
    mm[0] = m1;
    mm[1] = fmaxf(e, ALPHA * e);
  }
}

// ---------------------------------------------------------------------------
// Kernel 3: factor tables (split-shift keeps every factor <= 1, fp16-safe):
//   Fi[i] = half2{ 2^(s1-m1), 2^(.2(s1-m1)) }
//   TT[j/4] = 16B { T1[j..j+3], T2[j..j+3] }, T1 = 2^(s2-(ML-m1)),
//   T2 = 2^(.2*s2-(ML-.2*m1));  F1*T1 = 2^(s1+s2-ML), F2*T2 = 2^(.2(s1+s2)-ML)
// ---------------------------------------------------------------------------
__global__ __launch_bounds__(256) void ftab_kernel(
    const float* __restrict__ s1L, const float* __restrict__ s2L,
    const float* __restrict__ mm, unsigned int* __restrict__ Fi,
    _Float16* __restrict__ TTh) {
  const int j = blockIdx.x * 256 + threadIdx.x;
  const float m1 = mm[0], ML = mm[1];

  const float v1 = s1L[j] - m1;
  h2 f;
  f[0] = (_Float16)exp2f(v1);
  f[1] = (_Float16)exp2f(0.2f * v1);
  Fi[j] = __builtin_bit_cast(unsigned int, f);

  TTh[(j >> 2) * 8 + (j & 3)]     = (_Float16)exp2f(s2L[j] - (ML - m1));
  TTh[(j >> 2) * 8 + 4 + (j & 3)] =
      (_Float16)exp2f(0.2f * s2L[j] - (ML - 0.2f * m1));
}

// ---------------------------------------------------------------------------
// Kernel 4: pack B-fragments: Bpack[((kt*4+fg)*64+lane)*8] <- Wh_t frag.
// ---------------------------------------------------------------------------
__global__ __launch_bounds__(256) void bpack_kernel(
    const _Float16* __restrict__ Wh_t, _Float16* __restrict__ Bpack) {
  const int kt = blockIdx.x;
  const int t = threadIdx.x;
  const int fg = t >> 6;
  const int lane = t & 63;
  const int q = (t >> 4) & 3;
  const int r16 = t & 15;
  const half8 v =
      *(const half8*)(Wh_t + (size_t)(fg * 16 + r16) * N + kt * 32 + q * 8);
  *(half8*)(Bpack + ((size_t)(kt * 4 + fg) * 64 + lane) * 8) = v;
}

// ---------------------------------------------------------------------------
// Kernel 5: adj streamer. grid (N/64, JC); wave w: rows i0..i0+15,
// chunk cols [c*1024,+1024) in 4 k-tiles of 256. Every adj load is one row x
// 1 KB lane-contiguous. Per-wave LDS (no barriers).
// ---------------------------------------------------------------------------
__global__ __launch_bounds__(256, 4) void attn_kernel(
    const int* __restrict__ adj, const _Float16* __restrict__ Bpack,
    const unsigned int* __restrict__ Fi, const uint4* __restrict__ TT,
    float* __restrict__ accp, float* __restrict__ lp) {
  __shared__ __align__(16) _Float16 Ps[4 * 16 * LDP];  // 33792 B

  const int t = threadIdx.x;
  const int w = t >> 6;
  const int lane = t & 63;
  const int q = lane >> 4;
  const int r16 = lane & 15;
  const int i0 = blockIdx.x * 64 + w * 16;
  const int c = blockIdx.y;
  const int jb = c * (N / JC);  // 1024-col chunk

  _Float16* Pw = Ps + w * 16 * LDP;
  const _Float16* ldA = Pw + r16 * LDP + q * 8;

  half8 bones;
#pragma unroll
  for (int e = 0; e < 8; ++e)
    bones[e] = (r16 == 0) ? (_Float16)1.0f : (_Float16)0.0f;

  const unsigned fi_all = Fi[i0 + r16];  // rows 0..15 live in lanes 0..15
  const int* apb = adj + (size_t)i0 * N + jb + lane * 4;
  const uint4* ttb = TT + (jb >> 2) + lane;

  f32x4 acc[5] = {{0.f, 0.f, 0.f, 0.f}, {0.f, 0.f, 0.f, 0.f},
                  {0.f, 0.f, 0.f, 0.f}, {0.f, 0.f, 0.f, 0.f},
                  {0.f, 0.f, 0.f, 0.f}};

  for (int jt = 0; jt < 4; ++jt) {  // k-tiles of 256 cols
    const uint4 tt = ttb[jt * 64];  // this lane's 4 cols: T1 x4 | T2 x4

    // P build: 16 loads, each ONE row x 1 KB fully lane-contiguous
#pragma unroll
    for (int b = 0; b < 4; ++b) {
      int4 av[4];
#pragma unroll
      for (int rr = 0; rr < 4; ++rr)
        av[rr] = *(const int4*)(apb + (size_t)(b * 4 + rr) * N + jt * 256);
#pragma unroll
      for (int rr = 0; rr < 4; ++rr) {
        const int row = b * 4 + rr;
        const unsigned u = __shfl(fi_all, row);
        const h2 f1 = bc_h2((u & 0xFFFFu) * 0x00010001u);
        const h2 f2 = bc_h2((u >> 16) * 0x00010001u);
        const unsigned mlo = (unsigned)(av[rr].x | (av[rr].y << 16)) * 0x3C00u;
        const unsigned mhi = (unsigned)(av[rr].z | (av[rr].w << 16)) * 0x3C00u;
        const h2 plo =
            __builtin_elementwise_max(f1 * bc_h2(tt.x), f2 * bc_h2(tt.z)) *
            bc_h2(mlo);
        const h2 phi =
            __builtin_elementwise_max(f1 * bc_h2(tt.y), f2 * bc_h2(tt.w)) *
            bc_h2(mhi);
        uint2 pw;
        pw.x = __builtin_bit_cast(unsigned, plo);
        pw.y = __builtin_bit_cast(unsigned, phi);
        *(uint2*)(Pw + row * LDP + lane * 4) = pw;  // stride-1 row: conflict-free
      }
    }

    // MFMA: 8 k-steps of 32; A from per-wave LDS (same-wave order, no
    // barrier), B from L2-hot Bpack (+ ones column -> row sums)
    const int ktb = c * 32 + jt * 8;
#pragma unroll
    for (int ks = 0; ks < 8; ++ks) {
      const half8 aF = *(const half8*)(ldA + ks * 32);
      const _Float16* bp = Bpack + ((size_t)((ktb + ks) * 4) * 64 + lane) * 8;
#pragma unroll
      for (int fg = 0; fg < 4; ++fg) {
        const half8 bf = *(const half8*)(bp + (size_t)fg * 512);
        acc[fg] =
            __builtin_amdgcn_mfma_f32_16x16x32_f16(aF, bf, acc[fg], 0, 0, 0);
      }
      acc[4] =
          __builtin_amdgcn_mfma_f32_16x16x32_f16(aF, bones, acc[4], 0, 0, 0);
    }
  }

  // store partials. C/D: row = q*4+r, col = r16 (per fg block)
#pragma unroll
  for (int fg = 0; fg < 4; ++fg) {
#pragma unroll
    for (int r = 0; r < 4; ++r) {
      accp[((size_t)c * N + i0 + q * 4 + r) * OUT_DIM + fg * 16 + r16] =
          acc[fg][r];
    }
  }
  if (r16 == 0) {
#pragma unroll
    for (int r = 0; r < 4; ++r) lp[(size_t)c * N + i0 + q * 4 + r] = acc[4][r];
  }
}

// ---------------------------------------------------------------------------
// Kernel 6: combine JC partials, normalize, ELU.
// ---------------------------------------------------------------------------
__global__ __launch_bounds__(256) void reduce_kernel(
    const float* __restrict__ accp, const float* __restrict__ lp,
    float* __restrict__ out) {
  const int tid = blockIdx.x * 256 + threadIdx.x;
  const int i = tid >> 6;
  float s = 0.f, l = 0.f;
#pragma unroll
  for (int c = 0; c < JC; ++c) s += accp[(size_t)c * N * OUT_DIM + tid];
#pragma unroll
  for (int c = 0; c < JC; ++c) l += lp[(size_t)c * N + i];
  float v = s / l;
  out[tid] = v > 0.f ? v : expm1f(v);
}

// ---------------------------------------------------------------------------
extern "C" void kernel_launch(void* const* d_in, const int* in_sizes, int n_in,
                              void* d_out, int out_size, void* d_ws,
                              size_t ws_size, hipStream_t stream) {
  const float* x = (const float*)d_in[0];
  const int* adj = (const int*)d_in[1];
  const float* W = (const float*)d_in[2];
  const float* a = (const float*)d_in[3];
  float* out = (float*)d_out;

  char* ws = (char*)d_ws;
  _Float16* Wh_t = (_Float16*)ws;                       // 1 MiB
  float* s1L = (float*)(ws + (1u << 20));               // 32 KiB
  float* s2L = (float*)(ws + (1u << 20) + (64u << 10)); // 32 KiB
  float* mm = (float*)(ws + (1u << 20) + (128u << 10)); // 8 B
  unsigned* Fi = (unsigned*)(ws + (1u << 20) + (192u << 10));   // 32 KiB
  _Float16* TTh = (_Float16*)(ws + (1u << 20) + (256u << 10));  // 32 KiB
  _Float16* Bpack = (_Float16*)(ws + (2u << 20));       // 1 MiB
  float* accp = (float*)(ws + (4u << 20));              // JC*N*64*4 = 16 MiB
  float* lp = (float*)(ws + (20u << 20));               // 256 KiB

  wh_kernel<<<N, 64, 0, stream>>>(x, W, a, Wh_t, s1L, s2L);
  max_kernel<<<1, 256, 0, stream>>>(s1L, s2L, mm);
  ftab_kernel<<<N / 256, 256, 0, stream>>>(s1L, s2L, mm, Fi, TTh);
  bpack_kernel<<<N / 32, 256, 0, stream>>>(Wh_t, Bpack);
  attn_kernel<<<dim3(N / 64, JC), 256, 0, stream>>>(
      adj, Bpack, Fi, (const uint4*)TTh, accp, lp);
  reduce_kernel<<<N * OUT_DIM / 256, 256, 0, stream>>>(accp, lp, out);
}